// Round 12
// baseline (78.597 us; speedup 1.0000x reference)
//
#include <hip/hip_runtime.h>

#define NEXP  64
#define NTOK  32768
#define TOPK  2
#define NFLAT (NTOK * TOPK)   // 65536
#define DM    1024
#define NBLK  256
#define EPB   (NFLAT / NBLK)  // 256

typedef float v4f __attribute__((ext_vector_type(4)));

// Output layout (float32, concatenated):
#define O1 ((size_t)NFLAT * DM)
#define O2 (O1 + NFLAT)
#define O3 (O2 + NFLAT)

// ws layout (ints)
#define WS_DET 0                        // NBLK per-block detect OR slots
#define WS_H32 (WS_DET + NBLK)          // NBLK*NEXP histograms (int32 hyp.)
#define WS_H64 (WS_H32 + NBLK * NEXP)   // NBLK*NEXP histograms (int64 hyp.)

// Combined detect + dual-hypothesis histogram. Block b:
//  - odd-word OR over words [256b, 256b+256)  -> det slot (int64 => all 0)
//  - hist32 from words [256b, 256b+256)        (entries if layout is int32)
//  - hist64 from even words of [512b, 512b+512) (entries if layout is int64)
__global__ void k_hist(const int* __restrict__ routing, int* __restrict__ ws) {
    __shared__ int h32[NEXP], h64[NEXP];
    __shared__ int oSh;
    const int t = threadIdx.x;
    const int b = blockIdx.x;
    if (t == 0) oSh = 0;
    if (t < NEXP) { h32[t] = 0; h64[t] = 0; }
    __syncthreads();
    int w32 = routing[b * EPB + t];
    int w64 = routing[(size_t)(b * EPB + t) * 2];
    int odd = (t & 1) ? w32 : 0;
    if (__any(odd != 0)) { if ((t & 63) == 0) atomicOr(&oSh, 1); }
    atomicAdd(&h32[w32 & 63], 1);
    atomicAdd(&h64[w64 & 63], 1);
    __syncthreads();
    if (t == 0) ws[WS_DET + b] = oSh;
    if (t < NEXP) {
        ws[WS_H32 + b * NEXP + t] = h32[t];
        ws[WS_H64 + b * NEXP + t] = h64[t];
    }
}

// Fused: stride resolve + per-block expert base offsets + stable-rank
// scatter + row copy. Block b owns entries [256b,256b+256) = tokens
// [128b, 128b+128). 1024 threads: prep uses first 256, copy uses all
// (16 waves/CU doubles outstanding LLC loads vs 512).
__global__ void __launch_bounds__(1024)
k_main(const int* __restrict__ routing, const int* __restrict__ ws,
       const float* __restrict__ hidden, float* __restrict__ out) {
    __shared__ int se[EPB];
    __shared__ int dstSh[EPB];
    __shared__ int s1h[4][NEXP], s2h[4][NEXP];
    __shared__ int boSh[NEXP];
    __shared__ int flagSh;
    const int t = threadIdx.x;
    const int b = blockIdx.x;

    // Resolve stride from the 256 det slots (any nonzero -> int32).
    if (t == 0) flagSh = 0;
    __syncthreads();
    if (t < NBLK && ws[WS_DET + t] != 0) atomicOr(&flagSh, 1);
    __syncthreads();
    const int stride = flagSh ? 1 : 2;           // 1=int32, 2=int64 words
    const int hbase = flagSh ? WS_H32 : WS_H64;  // matching histogram table

    if (t < EPB) {
        int i = b * EPB + t;
        se[t] = routing[(size_t)i * stride];
    }
    // Expert base offsets: wave c sums hist quarter [64c, 64c+64).
    if (t < 256) {
        int e = t & 63, c = t >> 6;
        int s1 = 0, s2 = 0;
        #pragma unroll 8
        for (int r = c * 64; r < c * 64 + 64; ++r) {
            int v = ws[hbase + r * NEXP + e];
            s2 += v;
            s1 += (r < b) ? v : 0;
        }
        s1h[c][e] = s1; s2h[c][e] = s2;
    }
    __syncthreads();
    if (t < 64) {
        int e = t;
        int pre = s1h[0][e] + s1h[1][e] + s1h[2][e] + s1h[3][e];
        int tot = s2h[0][e] + s2h[1][e] + s2h[2][e] + s2h[3][e];
        int x = tot;
        #pragma unroll
        for (int d = 1; d < 64; d <<= 1) {
            int y = __shfl_up(x, d, 64);
            if (e >= d) x += y;
        }
        boSh[e] = (x - tot) + pre;          // expert prefix + prior blocks
        if (b == 0) out[O3 + e] = (float)tot;
    }
    __syncthreads();
    // Stable rank within block + index outputs.
    if (t < EPB) {
        int e = se[t];
        int rank = 0;
        for (int j = 0; j < t; ++j) rank += (se[j] == e) ? 1 : 0;
        int dst = boSh[e] + rank;
        dstSh[t] = dst;
        int i = b * EPB + t;
        out[O1 + dst] = (float)i;
        out[O2 + i] = (float)i;
    }
    __syncthreads();
    // Copy: temporal loads (hidden LLC-resident across replays),
    // nontemporal stores (write-once stream; no RFO, no LLC pollution).
    // 1024 threads: 4 tokens per iteration, 32 iterations.
    const int quarter = t >> 8;  // which of 4 tokens this iteration
    const int lt = t & 255;      // float4 slot within the row
    #pragma unroll 4
    for (int k = 0; k < 128; k += 4) {
        int tokLocal = k + quarter;
        int tok = b * 128 + tokLocal;
        const v4f* src = (const v4f*)(hidden + (size_t)tok * DM);
        v4f v = src[lt];
        int d0 = dstSh[2 * tokLocal];
        int d1 = dstSh[2 * tokLocal + 1];
        __builtin_nontemporal_store(v, (v4f*)(out + (size_t)d0 * DM) + lt);
        __builtin_nontemporal_store(v, (v4f*)(out + (size_t)d1 * DM) + lt);
    }
}

extern "C" void kernel_launch(void* const* d_in, const int* in_sizes, int n_in,
                              void* d_out, int out_size, void* d_ws, size_t ws_size,
                              hipStream_t stream) {
    const float* hidden = (const float*)d_in[0];
    const int* routing = (const int*)d_in[1];
    float* out = (float*)d_out;
    int* ws = (int*)d_ws;

    k_hist<<<NBLK, EPB, 0, stream>>>(routing, ws);
    k_main<<<NBLK, 1024, 0, stream>>>(routing, ws, hidden, out);
}

// Round 13
// 77.063 us; speedup vs baseline: 1.0199x; 1.0199x over previous
//
#include <hip/hip_runtime.h>

#define NEXP  64
#define NTOK  32768
#define TOPK  2
#define NFLAT (NTOK * TOPK)   // 65536
#define DM    1024
#define NBLK  256
#define EPB   (NFLAT / NBLK)  // 256
#define PF    8               // prefetch depth (v4f regs/thread)

typedef float v4f __attribute__((ext_vector_type(4)));

// Output layout (float32, concatenated):
#define O1 ((size_t)NFLAT * DM)
#define O2 (O1 + NFLAT)
#define O3 (O2 + NFLAT)

// ws layout (ints)
#define WS_DET 0                        // NBLK per-block detect OR slots
#define WS_H32 (WS_DET + NBLK)          // NBLK*NEXP histograms (int32 hyp.)
#define WS_H64 (WS_H32 + NBLK * NEXP)   // NBLK*NEXP histograms (int64 hyp.)

// Combined detect + dual-hypothesis histogram. Block b:
//  - odd-word OR over words [256b, 256b+256)  -> det slot (int64 => all 0)
//  - hist32 from words [256b, 256b+256)        (entries if layout is int32)
//  - hist64 from even words of [512b, 512b+512) (entries if layout is int64)
__global__ void k_hist(const int* __restrict__ routing, int* __restrict__ ws) {
    __shared__ int h32[NEXP], h64[NEXP];
    __shared__ int oSh;
    const int t = threadIdx.x;
    const int b = blockIdx.x;
    if (t == 0) oSh = 0;
    if (t < NEXP) { h32[t] = 0; h64[t] = 0; }
    __syncthreads();
    int w32 = routing[b * EPB + t];
    int w64 = routing[(size_t)(b * EPB + t) * 2];
    int odd = (t & 1) ? w32 : 0;
    if (__any(odd != 0)) { if ((t & 63) == 0) atomicOr(&oSh, 1); }
    atomicAdd(&h32[w32 & 63], 1);
    atomicAdd(&h64[w64 & 63], 1);
    __syncthreads();
    if (t == 0) ws[WS_DET + b] = oSh;
    if (t < NEXP) {
        ws[WS_H32 + b * NEXP + t] = h32[t];
        ws[WS_H64 + b * NEXP + t] = h64[t];
    }
}

// Fused: stride resolve + per-block expert base offsets + stable-rank
// scatter + software-pipelined row copy. Block b owns entries
// [256b, 256b+256) = tokens [128b, 128b+128).
__global__ void __launch_bounds__(512)
k_main(const int* __restrict__ routing, const int* __restrict__ ws,
       const float* __restrict__ hidden, float* __restrict__ out) {
    __shared__ int se[EPB];
    __shared__ int dstSh[EPB];
    __shared__ int s1h[4][NEXP], s2h[4][NEXP];
    __shared__ int boSh[NEXP];
    __shared__ int flagSh;
    const int t = threadIdx.x;
    const int b = blockIdx.x;
    const int half = t >> 8;     // which of 2 tokens per copy iteration
    const int lt = t & 255;      // float4 slot within the row

    // ---- Issue copy-source prefetch FIRST: addresses are routing-independent,
    // so these HBM/LLC loads fly while prep computes below.
    v4f pf[PF];
    #pragma unroll
    for (int it = 0; it < PF; ++it) {
        int tok = b * 128 + it * 2 + half;
        pf[it] = ((const v4f*)(hidden + (size_t)tok * DM))[lt];
    }

    // ---- Resolve stride from the 256 det slots (any nonzero -> int32).
    if (t == 0) flagSh = 0;
    __syncthreads();
    if (t < NBLK && ws[WS_DET + t] != 0) atomicOr(&flagSh, 1);
    __syncthreads();
    const int stride = flagSh ? 1 : 2;           // 1=int32, 2=int64 words
    const int hbase = flagSh ? WS_H32 : WS_H64;  // matching histogram table

    if (t < EPB) {
        int i = b * EPB + t;
        se[t] = routing[(size_t)i * stride];
    }
    // Expert base offsets: wave c sums hist quarter [64c, 64c+64).
    if (t < 256) {
        int e = t & 63, c = t >> 6;
        int s1 = 0, s2 = 0;
        #pragma unroll 8
        for (int r = c * 64; r < c * 64 + 64; ++r) {
            int v = ws[hbase + r * NEXP + e];
            s2 += v;
            s1 += (r < b) ? v : 0;
        }
        s1h[c][e] = s1; s2h[c][e] = s2;
    }
    __syncthreads();
    if (t < 64) {
        int e = t;
        int pre = s1h[0][e] + s1h[1][e] + s1h[2][e] + s1h[3][e];
        int tot = s2h[0][e] + s2h[1][e] + s2h[2][e] + s2h[3][e];
        int x = tot;
        #pragma unroll
        for (int d = 1; d < 64; d <<= 1) {
            int y = __shfl_up(x, d, 64);
            if (e >= d) x += y;
        }
        boSh[e] = (x - tot) + pre;          // expert prefix + prior blocks
        if (b == 0) out[O3 + e] = (float)tot;
    }
    __syncthreads();
    // Stable rank within block + index outputs.
    if (t < EPB) {
        int e = se[t];
        int rank = 0;
        for (int j = 0; j < t; ++j) rank += (se[j] == e) ? 1 : 0;
        int dst = boSh[e] + rank;
        dstSh[t] = dst;
        int i = b * EPB + t;
        out[O1 + dst] = (float)i;
        out[O2 + i] = (float)i;
    }
    __syncthreads();

    // ---- Copy: 64 fully-unrolled iterations, 8-deep pipeline.
    // Temporal loads (hidden LLC-resident across replays), nontemporal
    // stores (write-once stream; no RFO, no LLC pollution).
    #pragma unroll
    for (int it = 0; it < 64; ++it) {
        v4f v = pf[it & (PF - 1)];
        int tokLocal = it * 2 + half;
        if (it + PF < 64) {
            int tok = b * 128 + (it + PF) * 2 + half;
            pf[it & (PF - 1)] = ((const v4f*)(hidden + (size_t)tok * DM))[lt];
        }
        int d0 = dstSh[2 * tokLocal];
        int d1 = dstSh[2 * tokLocal + 1];
        __builtin_nontemporal_store(v, (v4f*)(out + (size_t)d0 * DM) + lt);
        __builtin_nontemporal_store(v, (v4f*)(out + (size_t)d1 * DM) + lt);
    }
}

extern "C" void kernel_launch(void* const* d_in, const int* in_sizes, int n_in,
                              void* d_out, int out_size, void* d_ws, size_t ws_size,
                              hipStream_t stream) {
    const float* hidden = (const float*)d_in[0];
    const int* routing = (const int*)d_in[1];
    float* out = (float*)d_out;
    int* ws = (int*)d_ws;

    k_hist<<<NBLK, EPB, 0, stream>>>(routing, ws);
    k_main<<<NBLK, 512, 0, stream>>>(routing, ws, hidden, out);
}

// Round 14
// 74.681 us; speedup vs baseline: 1.0524x; 1.0319x over previous
//
#include <hip/hip_runtime.h>

#define NEXP  64
#define NTOK  32768
#define TOPK  2
#define NFLAT (NTOK * TOPK)   // 65536
#define DM    1024
#define NBLK  256
#define EPB   (NFLAT / NBLK)  // 256

typedef float v4f __attribute__((ext_vector_type(4)));

// Output layout (float32, concatenated):
#define O1 ((size_t)NFLAT * DM)
#define O2 (O1 + NFLAT)
#define O3 (O2 + NFLAT)

// ws layout (ints)
#define WS_DET 0                        // NBLK per-block detect OR slots
#define WS_H32 (WS_DET + NBLK)          // NBLK*NEXP histograms (int32 hyp.)
#define WS_H64 (WS_H32 + NBLK * NEXP)   // NBLK*NEXP histograms (int64 hyp.)

// Combined detect + dual-hypothesis histogram. Block b:
//  - odd-word OR over words [256b, 256b+256)  -> det slot (int64 => all 0)
//  - hist32 from words [256b, 256b+256)        (entries if layout is int32)
//  - hist64 from even words of [512b, 512b+512) (entries if layout is int64)
__global__ void k_hist(const int* __restrict__ routing, int* __restrict__ ws) {
    __shared__ int h32[NEXP], h64[NEXP];
    __shared__ int oSh;
    const int t = threadIdx.x;
    const int b = blockIdx.x;
    if (t == 0) oSh = 0;
    if (t < NEXP) { h32[t] = 0; h64[t] = 0; }
    __syncthreads();
    int w32 = routing[b * EPB + t];
    int w64 = routing[(size_t)(b * EPB + t) * 2];
    int odd = (t & 1) ? w32 : 0;
    if (__any(odd != 0)) { if ((t & 63) == 0) atomicOr(&oSh, 1); }
    atomicAdd(&h32[w32 & 63], 1);
    atomicAdd(&h64[w64 & 63], 1);
    __syncthreads();
    if (t == 0) ws[WS_DET + b] = oSh;
    if (t < NEXP) {
        ws[WS_H32 + b * NEXP + t] = h32[t];
        ws[WS_H64 + b * NEXP + t] = h64[t];
    }
}

// Fused: stride resolve + per-block expert base offsets + stable-rank
// scatter + row copy. Block b owns entries [256b,256b+256) = tokens
// [128b, 128b+128).
__global__ void __launch_bounds__(512)
k_main(const int* __restrict__ routing, const int* __restrict__ ws,
       const float* __restrict__ hidden, float* __restrict__ out) {
    __shared__ int se[EPB];
    __shared__ int dstSh[EPB];
    __shared__ int s1h[4][NEXP], s2h[4][NEXP];
    __shared__ int boSh[NEXP];
    __shared__ int flagSh;
    const int t = threadIdx.x;
    const int b = blockIdx.x;

    // Resolve stride from the 256 det slots (any nonzero -> int32).
    if (t == 0) flagSh = 0;
    __syncthreads();
    if (t < NBLK && ws[WS_DET + t] != 0) atomicOr(&flagSh, 1);
    __syncthreads();
    const int stride = flagSh ? 1 : 2;           // 1=int32, 2=int64 words
    const int hbase = flagSh ? WS_H32 : WS_H64;  // matching histogram table

    if (t < EPB) {
        int i = b * EPB + t;
        se[t] = routing[(size_t)i * stride];
    }
    // Expert base offsets: wave c sums hist quarter [64c, 64c+64).
    if (t < 256) {
        int e = t & 63, c = t >> 6;
        int s1 = 0, s2 = 0;
        #pragma unroll 8
        for (int r = c * 64; r < c * 64 + 64; ++r) {
            int v = ws[hbase + r * NEXP + e];
            s2 += v;
            s1 += (r < b) ? v : 0;
        }
        s1h[c][e] = s1; s2h[c][e] = s2;
    }
    __syncthreads();
    if (t < 64) {
        int e = t;
        int pre = s1h[0][e] + s1h[1][e] + s1h[2][e] + s1h[3][e];
        int tot = s2h[0][e] + s2h[1][e] + s2h[2][e] + s2h[3][e];
        int x = tot;
        #pragma unroll
        for (int d = 1; d < 64; d <<= 1) {
            int y = __shfl_up(x, d, 64);
            if (e >= d) x += y;
        }
        boSh[e] = (x - tot) + pre;          // expert prefix + prior blocks
        if (b == 0) out[O3 + e] = (float)tot;
    }
    __syncthreads();
    // Stable rank within block + index outputs.
    if (t < EPB) {
        int e = se[t];
        int rank = 0;
        for (int j = 0; j < t; ++j) rank += (se[j] == e) ? 1 : 0;
        int dst = boSh[e] + rank;
        dstSh[t] = dst;
        int i = b * EPB + t;
        out[O1 + dst] = (float)i;
        out[O2 + i] = (float)i;
    }
    __syncthreads();
    // Copy: temporal loads (hidden LLC-resident across replays),
    // nontemporal stores (write-once stream; no RFO, no LLC pollution).
    const int half = t >> 8;     // which of 2 tokens this iteration
    const int lt = t & 255;      // float4 slot within the row
    #pragma unroll 4
    for (int k = 0; k < 128; k += 2) {
        int tokLocal = k + half;
        int tok = b * 128 + tokLocal;
        const v4f* src = (const v4f*)(hidden + (size_t)tok * DM);
        v4f v = src[lt];
        int d0 = dstSh[2 * tokLocal];
        int d1 = dstSh[2 * tokLocal + 1];
        __builtin_nontemporal_store(v, (v4f*)(out + (size_t)d0 * DM) + lt);
        __builtin_nontemporal_store(v, (v4f*)(out + (size_t)d1 * DM) + lt);
    }
}

extern "C" void kernel_launch(void* const* d_in, const int* in_sizes, int n_in,
                              void* d_out, int out_size, void* d_ws, size_t ws_size,
                              hipStream_t stream) {
    const float* hidden = (const float*)d_in[0];
    const int* routing = (const int*)d_in[1];
    float* out = (float*)d_out;
    int* ws = (int*)d_ws;

    k_hist<<<NBLK, EPB, 0, stream>>>(routing, ws);
    k_main<<<NBLK, 512, 0, stream>>>(routing, ws, hidden, out);
}